// Round 10
// baseline (1508.455 us; speedup 1.0000x reference)
//
#include <hip/hip_runtime.h>
#include <stdint.h>
#include <math.h>

typedef __attribute__((ext_vector_type(8))) short short8;
typedef __attribute__((ext_vector_type(4))) float float4v;

__device__ __forceinline__ uint16_t f2bf(float f){
  union { float f; uint32_t i; } c; c.f = f;
  uint32_t r = c.i + 0x7fffu + ((c.i >> 16) & 1u);   // round-to-nearest-even
  return (uint16_t)(r >> 16);
}
__device__ __forceinline__ uint32_t pack2(float lo, float hi){
  return (uint32_t)f2bf(lo) | ((uint32_t)f2bf(hi) << 16);
}
__device__ __forceinline__ void acc_bf2(uint32_t w, float& x, float& y){
  union { uint32_t i; float f; } a, b;
  a.i = w << 16; b.i = w & 0xffff0000u;
  x += a.f; y += b.f;
}

// ---- prep: LDS-staged bucket binning (64-node buckets) + bf16 conversion ---
// Edges packed src|dst<<16 (n<=65536), bucket = dst>>6 (up to 1024 buckets).
// Each 4096-edge block: LDS hist(1024) -> 2-level scan -> bucket-sorted LDS
// stage -> reserve per-bucket global ranges -> coalesced dump (r6 measured:
// naive 4-B scatter = 16x HBM write amplification; this avoids it).

__global__ __launch_bounds__(512) void prep_kernel(
    const int* __restrict__ ei, int E, int NB, int CAP, int p1blk,
    int* __restrict__ fill, uint32_t* __restrict__ bins,
    const float* __restrict__ x,
    const float* __restrict__ w0, const float* __restrict__ w1,
    const float* __restrict__ w2, const float* __restrict__ w3,
    const float* __restrict__ w4, const float* __restrict__ w5,
    uint16_t* __restrict__ xb, uint16_t* __restrict__ wb, int nx){
  if ((int)blockIdx.x < p1blk){
    __shared__ int hist[1024], excl[1024], cur[1024], gbase[1024];
    __shared__ int part[512];
    __shared__ uint32_t stage[4096];
    int tid = threadIdx.x;
    hist[tid] = 0; hist[tid + 512] = 0;
    __syncthreads();
    int e0 = blockIdx.x * 4096;
    int nval = E - e0; if (nval > 4096) nval = 4096;
    uint32_t w[8]; int bk[8];
    #pragma unroll
    for (int k = 0; k < 8; ++k){
      int e = e0 + k * 512 + tid;
      bool ok = e < E;
      int s = ok ? ei[e] : 0;
      int d = ok ? ei[E + e] : 0;
      w[k] = (uint32_t)s | ((uint32_t)d << 16);
      bk[k] = ok ? (d >> 6) : -1;
      if (ok) atomicAdd(&hist[bk[k]], 1);
    }
    __syncthreads();
    // 1024-wide exclusive scan: pair-sums -> 512 Hillis-Steele -> expand
    int h0 = hist[2 * tid], h1 = hist[2 * tid + 1];
    part[tid] = h0 + h1;
    __syncthreads();
    #pragma unroll
    for (int off = 1; off < 512; off <<= 1){
      int v = 0;
      if (tid >= off) v = part[tid - off];
      __syncthreads();
      part[tid] += v;
      __syncthreads();
    }
    int pex = part[tid] - (h0 + h1);       // exclusive prefix over pairs
    excl[2 * tid] = pex;        cur[2 * tid] = pex;
    excl[2 * tid + 1] = pex + h0; cur[2 * tid + 1] = pex + h0;
    __syncthreads();
    #pragma unroll
    for (int bi = 0; bi < 2; ++bi){
      int b = tid + bi * 512;
      gbase[b] = (b < NB && hist[b] > 0) ? atomicAdd(&fill[b], hist[b]) : 0;
    }
    __syncthreads();
    #pragma unroll
    for (int k = 0; k < 8; ++k){
      if (bk[k] >= 0){
        int p = atomicAdd(&cur[bk[k]], 1);
        stage[p] = w[k];
      }
    }
    __syncthreads();
    for (int i = tid; i < nval; i += 512){
      uint32_t v = stage[i];
      int b = (int)(v >> 22);              // dst>>6
      int loc = gbase[b] + (i - excl[b]);
      if (loc < CAP)
        __builtin_nontemporal_store(v, bins + (size_t)b * CAP + loc);
    }
  } else {
    int i = (blockIdx.x - p1blk) * 512 + threadIdx.x;
    int stride = (gridDim.x - p1blk) * 512;
    // x fp32 -> bf16 row-major; float4 reads, uint2 (4xbf16) writes
    for (int j = i; j < (nx >> 2); j += stride){
      float4 v = ((const float4*)x)[j];
      uint2 o;
      o.x = pack2(v.x, v.y); o.y = pack2(v.z, v.w);
      ((uint2*)xb)[j] = o;
    }
    const int WSZ = 128 * 128;
    for (int j = i; j < 6 * WSZ; j += stride){
      int t = j >> 14, o = j & (WSZ - 1);
      const float* w = t == 0 ? w0 : t == 1 ? w1 : t == 2 ? w2 : t == 3 ? w3 : t == 4 ? w4 : w5;
      wb[j] = f2bf(w[o]);
    }
  }
}

// ---- fused aggregate: one block per 64-node bucket, LDS fp32 accumulators --
// Replaces build+agg: bucket's edges are contiguous in bins (coalesced read);
// gather keeps the r0-proven shape (16 lanes x 16B = 256B row, 4 gathers in
// flight per lane); accumulation via LDS atomicAdd f32 rides the DS pipe and
// hides under the fabric-bound gather. Epilogue: mean -> bf16 -> one fully
// coalesced 16 KB store per block. LDS ~34 KB -> 4 blocks/CU, 24-32 waves/CU.

#define AC_STRIDE 132   // floats per acc row (128 + 4 pad: spreads sub banks)

__device__ __forceinline__ void addw(float* a, uint32_t w){
  union { uint32_t i; float f; } lo, hi;
  lo.i = w << 16; hi.i = w & 0xffff0000u;
  atomicAdd(a, lo.f); atomicAdd(a + 1, hi.f);
}
__device__ __forceinline__ void acc_edge(float* acc, int d, int fq, uint4 v){
  float* a = acc + d * AC_STRIDE + fq * 8;
  addw(a + 0, v.x); addw(a + 2, v.y); addw(a + 4, v.z); addw(a + 6, v.w);
}

__global__ __launch_bounds__(512) void aggb_kernel(const uint16_t* __restrict__ xin,
                                                   const uint32_t* __restrict__ bins,
                                                   const int* __restrict__ fill,
                                                   int CAP,
                                                   uint16_t* __restrict__ aggw,
                                                   int n){
  __shared__ float acc[64 * AC_STRIDE];
  __shared__ int deg[64];
  int b = blockIdx.x, tid = threadIdx.x;
  for (int i = tid; i < 64 * AC_STRIDE; i += 512) acc[i] = 0.f;
  if (tid < 64) deg[tid] = 0;
  __syncthreads();
  int cnt = fill[b]; if (cnt > CAP) cnt = CAP;
  size_t base = (size_t)b * CAP;
  int wid = tid >> 6, lane = tid & 63, sub = lane >> 4, fq = lane & 15;
  const uint4* xv = (const uint4*)xin;      // row = 16 x uint4 (256B)

  // 8 waves x 4 subs x 4 edges = 128 edges per block iteration
  for (int e = wid * 16 + sub * 4; e < cnt; e += 128){
    bool k1 = e + 1 < cnt, k2 = e + 2 < cnt, k3 = e + 3 < cnt;
    uint32_t p0 = bins[base + e];
    uint32_t p1 = k1 ? bins[base + e + 1] : p0;
    uint32_t p2 = k2 ? bins[base + e + 2] : p0;
    uint32_t p3 = k3 ? bins[base + e + 3] : p0;
    int s0 = p0 & 0xffff, d0 = (p0 >> 16) & 63;
    int s1 = p1 & 0xffff, d1 = (p1 >> 16) & 63;
    int s2 = p2 & 0xffff, d2 = (p2 >> 16) & 63;
    int s3 = p3 & 0xffff, d3 = (p3 >> 16) & 63;
    uint4 v0 = xv[(size_t)s0 * 16 + fq];    // 4 gathers in flight per lane
    uint4 v1 = xv[(size_t)s1 * 16 + fq];
    uint4 v2 = xv[(size_t)s2 * 16 + fq];
    uint4 v3 = xv[(size_t)s3 * 16 + fq];
    acc_edge(acc, d0, fq, v0);
    if (fq == 0) atomicAdd(&deg[d0], 1);
    if (k1){ acc_edge(acc, d1, fq, v1); if (fq == 0) atomicAdd(&deg[d1], 1); }
    if (k2){ acc_edge(acc, d2, fq, v2); if (fq == 0) atomicAdd(&deg[d2], 1); }
    if (k3){ acc_edge(acc, d3, fq, v3); if (fq == 0) atomicAdd(&deg[d3], 1); }
  }
  __syncthreads();

  // epilogue: mean -> bf16, thread covers 16 cols of one row; block writes
  // 16 KB fully contiguous (thread tid -> bytes [tid*32, tid*32+32)).
  int row = tid >> 3, c0 = (tid & 7) * 16;
  int node = b * 64 + row;
  if (node < n){
    float inv = 1.f / fmaxf((float)deg[row], 1.f);
    const float* a = acc + row * AC_STRIDE + c0;
    uint4 o1, o2;
    o1.x = pack2(a[0] * inv,  a[1] * inv);  o1.y = pack2(a[2] * inv,  a[3] * inv);
    o1.z = pack2(a[4] * inv,  a[5] * inv);  o1.w = pack2(a[6] * inv,  a[7] * inv);
    o2.x = pack2(a[8] * inv,  a[9] * inv);  o2.y = pack2(a[10] * inv, a[11] * inv);
    o2.z = pack2(a[12] * inv, a[13] * inv); o2.w = pack2(a[14] * inv, a[15] * inv);
    uint4* op = (uint4*)aggw + (size_t)node * 16 + (tid & 7) * 2;
    op[0] = o1; op[1] = o2;
  }
}

// ---- weight-staged GEMM tiles (verbatim r7) --------------------------------
// Block = 256 thr (4 waves) owns 64 rows and loops over ALL weight phases
// in-kernel: A-fragments loaded ONCE into registers; each 64-col weight slice
// staged into re-used LDS (34.8 KB -> 4 blocks/CU).
// MFMA 16x16x32 bf16, HW-verified layouts: A[m=lane&15][k=quad*8+j];
// B[k][n=lane&15] from W[col][k]; C/D col=lane&15, row=quad*4+reg.

#define WT_STRIDE 136   // shorts per staged weight row (128 + 8 pad)

__device__ __forceinline__ void stage_weights(const uint16_t* __restrict__ Wl,
                                              const uint16_t* __restrict__ Wr,
                                              int ch, uint16_t* lds_l,
                                              uint16_t* lds_r, int tid){
  const uint4* srcL = (const uint4*)(Wl + (size_t)(ch * 64) * 128);
  const uint4* srcR = (const uint4*)(Wr + (size_t)(ch * 64) * 128);
  #pragma unroll
  for (int i = 0; i < 4; ++i){          // 1024 uint4 per matrix / 256 thr
    int j = tid + i * 256;
    int row = j >> 4, c8 = j & 15;      // 16 uint4 per 128-col row
    uint4 vl = srcL[j], vr = srcR[j];
    *(uint4*)(lds_l + row * WT_STRIDE + c8 * 8) = vl;
    *(uint4*)(lds_r + row * WT_STRIDE + c8 * 8) = vr;
  }
}

// layer 1: x1 = relu(agg@W1l^T + b1 + x@W1r^T), bf16 out. ch looped in-kernel.
__global__ __launch_bounds__(256) void gemm1_kernel(
    const uint16_t* __restrict__ Aagg, const uint16_t* __restrict__ Ax,
    const uint16_t* __restrict__ Wl, const uint16_t* __restrict__ Wr,
    const float* __restrict__ bias, uint16_t* __restrict__ x1b, int n){
  __shared__ uint16_t lds_l[64 * WT_STRIDE], lds_r[64 * WT_STRIDE];
  int tid = threadIdx.x, lane = tid & 63, wid = tid >> 6;
  int m = lane & 15, quad = lane >> 4;
  int r0 = blockIdx.x * 64 + wid * 16;
  int arow = r0 + m; if (arow > n - 1) arow = n - 1;   // clamp tail reads

  short8 a0f[4], a1f[4];
  #pragma unroll
  for (int ks = 0; ks < 4; ++ks){
    a0f[ks] = *(const short8*)(Aagg + (size_t)arow * 128 + ks * 32 + quad * 8);
    a1f[ks] = *(const short8*)(Ax   + (size_t)arow * 128 + ks * 32 + quad * 8);
  }

  for (int ch = 0; ch < 2; ++ch){
    if (ch) __syncthreads();              // prior phase's LDS reads done
    stage_weights(Wl, Wr, ch, lds_l, lds_r, tid);
    __syncthreads();
    float4v acc[4];
    #pragma unroll
    for (int ct = 0; ct < 4; ++ct) acc[ct] = (float4v){0.f, 0.f, 0.f, 0.f};
    #pragma unroll
    for (int ks = 0; ks < 4; ++ks){
      #pragma unroll
      for (int ct = 0; ct < 4; ++ct){
        short8 b0 = *(const short8*)(lds_l + (ct * 16 + m) * WT_STRIDE + ks * 32 + quad * 8);
        acc[ct] = __builtin_amdgcn_mfma_f32_16x16x32_bf16(a0f[ks], b0, acc[ct], 0, 0, 0);
        short8 b1 = *(const short8*)(lds_r + (ct * 16 + m) * WT_STRIDE + ks * 32 + quad * 8);
        acc[ct] = __builtin_amdgcn_mfma_f32_16x16x32_bf16(a1f[ks], b1, acc[ct], 0, 0, 0);
      }
    }
    #pragma unroll
    for (int ct = 0; ct < 4; ++ct){
      int col = ch * 64 + ct * 16 + m;
      float bv = bias[col];
      #pragma unroll
      for (int i = 0; i < 4; ++i){
        int grow = r0 + quad * 4 + i;
        if (grow < n)
          x1b[(size_t)grow * 128 + col] = f2bf(fmaxf(acc[ct][i] + bv, 0.f));
      }
    }
  }
}

// layers 2+3: all 4 (pass, ch) phases looped in-kernel; A read once. fp32 out.
__global__ __launch_bounds__(256) void gemm23_kernel(
    const uint16_t* __restrict__ Aagg, const uint16_t* __restrict__ Ax,
    const uint16_t* __restrict__ W2l, const uint16_t* __restrict__ W2r,
    const float* __restrict__ b2,
    const uint16_t* __restrict__ W3l, const uint16_t* __restrict__ W3r,
    const float* __restrict__ b3,
    float* __restrict__ out, size_t half, int n){
  __shared__ uint16_t lds_l[64 * WT_STRIDE], lds_r[64 * WT_STRIDE];
  int tid = threadIdx.x, lane = tid & 63, wid = tid >> 6;
  int m = lane & 15, quad = lane >> 4;
  int r0 = blockIdx.x * 64 + wid * 16;
  int arow = r0 + m; if (arow > n - 1) arow = n - 1;

  short8 a0f[4], a1f[4];
  #pragma unroll
  for (int ks = 0; ks < 4; ++ks){
    a0f[ks] = *(const short8*)(Aagg + (size_t)arow * 128 + ks * 32 + quad * 8);
    a1f[ks] = *(const short8*)(Ax   + (size_t)arow * 128 + ks * 32 + quad * 8);
  }

  for (int idx = 0; idx < 4; ++idx){
    int pass = idx >> 1, ch = idx & 1;
    if (idx) __syncthreads();
    stage_weights(pass ? W3l : W2l, pass ? W3r : W2r, ch, lds_l, lds_r, tid);
    __syncthreads();
    float4v acc[4];
    #pragma unroll
    for (int ct = 0; ct < 4; ++ct) acc[ct] = (float4v){0.f, 0.f, 0.f, 0.f};
    #pragma unroll
    for (int ks = 0; ks < 4; ++ks){
      #pragma unroll
      for (int ct = 0; ct < 4; ++ct){
        short8 b0 = *(const short8*)(lds_l + (ct * 16 + m) * WT_STRIDE + ks * 32 + quad * 8);
        acc[ct] = __builtin_amdgcn_mfma_f32_16x16x32_bf16(a0f[ks], b0, acc[ct], 0, 0, 0);
        short8 b1 = *(const short8*)(lds_r + (ct * 16 + m) * WT_STRIDE + ks * 32 + quad * 8);
        acc[ct] = __builtin_amdgcn_mfma_f32_16x16x32_bf16(a1f[ks], b1, acc[ct], 0, 0, 0);
      }
    }
    const float* bb = pass ? b3 : b2;
    float* op = out + (pass ? half : 0);
    #pragma unroll
    for (int ct = 0; ct < 4; ++ct){
      int col = ch * 64 + ct * 16 + m;
      float bv = bb[col];
      #pragma unroll
      for (int i = 0; i < 4; ++i){
        int grow = r0 + quad * 4 + i;
        if (grow < n)
          __builtin_nontemporal_store(acc[ct][i] + bv,
                                      op + (size_t)grow * 128 + col);
      }
    }
  }
}

// ---- launcher --------------------------------------------------------------

extern "C" void kernel_launch(void* const* d_in, const int* in_sizes, int n_in,
                              void* d_out, int out_size, void* d_ws, size_t ws_size,
                              hipStream_t stream) {
  const float* x   = (const float*)d_in[0];   // fp32 [N,128]
  const int*   ei  = (const int*)d_in[1];     // int32 [2,E]
  const float* W1l = (const float*)d_in[2];
  const float* b1l = (const float*)d_in[3];
  const float* W1r = (const float*)d_in[4];
  const float* W2l = (const float*)d_in[5];
  const float* b2l = (const float*)d_in[6];
  const float* W2r = (const float*)d_in[7];
  const float* W3l = (const float*)d_in[8];
  const float* b3l = (const float*)d_in[9];
  const float* W3r = (const float*)d_in[10];
  float* out = (float*)d_out;

  const int n = in_sizes[0] / 128;
  const int E = in_sizes[1] / 2;
  const size_t half = (size_t)n * 128;        // elements per output half
  const int WSZ = 128 * 128;

  const int NB = (n + 63) >> 6;               // 64-node buckets (n <= 65536)
  int mean = (E + NB - 1) / NB;
  int CAP = mean + 8 * (int)sqrt((double)mean) + 64;
  CAP = (CAP + 63) & ~63;                     // per-bucket capacity, 8-sigma slack

  size_t off = 0;
  auto carve = [&](size_t bytes) -> void* {
    void* p = (char*)d_ws + off;
    off += (bytes + 255) & ~(size_t)255;
    return p;
  };
  int*      fill = (int*)carve((size_t)NB * 4);
  uint32_t* bins = (uint32_t*)carve((size_t)NB * CAP * 4);   // packed edges
  uint16_t* xb   = (uint16_t*)carve(half * 2);               // bf16 x
  uint16_t* wb   = (uint16_t*)carve((size_t)6 * WSZ * 2);    // bf16 weights
  uint16_t* x1b  = (uint16_t*)carve(half * 2);               // bf16 x1
  uint16_t* agg  = (uint16_t*)carve(half * 2);               // bf16 agg
  (void)ws_size;  // measured ws_size = 256 MiB >> ~35 MB used

  hipMemsetAsync(fill, 0, (size_t)NB * 4, stream);

  int p1blk = (E + 4095) / 4096;              // 4096 edges per binning block
  int cblk  = 512;                            // conversion blocks (grid-stride)
  prep_kernel<<<p1blk + cblk, 512, 0, stream>>>(ei, E, NB, CAP, p1blk, fill, bins,
                                                x, W1l, W1r, W2l, W2r, W3l, W3r,
                                                xb, wb, (int)half);

  int gblk = (n + 63) / 64;
  const uint16_t *Wb1l = wb, *Wb1r = wb + WSZ, *Wb2l = wb + 2 * WSZ,
                 *Wb2r = wb + 3 * WSZ, *Wb3l = wb + 4 * WSZ, *Wb3r = wb + 5 * WSZ;

  // layer 1 (aggregation fused with CSR elimination: one block per bucket)
  aggb_kernel<<<NB, 512, 0, stream>>>(xb, bins, fill, CAP, agg, n);
  gemm1_kernel<<<gblk, 256, 0, stream>>>(agg, xb, Wb1l, Wb1r, b1l, x1b, n);

  // shared aggregation of x1, then layers 2+3 in one launch
  aggb_kernel<<<NB, 512, 0, stream>>>(x1b, bins, fill, CAP, agg, n);
  gemm23_kernel<<<gblk, 256, 0, stream>>>(agg, x1b, Wb2l, Wb2r, b2l,
                                          Wb3l, Wb3r, b3l, out, half, n);
}

// Round 12
// 211.781 us; speedup vs baseline: 7.1227x; 7.1227x over previous
//
#include <hip/hip_runtime.h>
#include <stdint.h>
#include <math.h>

typedef __attribute__((ext_vector_type(8))) short short8;
typedef __attribute__((ext_vector_type(4))) float float4v;
typedef __attribute__((ext_vector_type(4))) float f32x4;

__device__ __forceinline__ uint16_t f2bf(float f){
  union { float f; uint32_t i; } c; c.f = f;
  uint32_t r = c.i + 0x7fffu + ((c.i >> 16) & 1u);   // round-to-nearest-even
  return (uint16_t)(r >> 16);
}
__device__ __forceinline__ uint32_t pack2(float lo, float hi){
  return (uint32_t)f2bf(lo) | ((uint32_t)f2bf(hi) << 16);
}
__device__ __forceinline__ void acc_bf2(uint32_t w, float& x, float& y){
  union { uint32_t i; float f; } a, b;
  a.i = w << 16; b.i = w & 0xffff0000u;
  x += a.f; y += b.f;
}
__device__ __forceinline__ void accum8(uint4 v, float* a){
  acc_bf2(v.x, a[0], a[1]); acc_bf2(v.y, a[2], a[3]);
  acc_bf2(v.z, a[4], a[5]); acc_bf2(v.w, a[6], a[7]);
}

// ---- prep: LDS-staged bucket binning + fp32->bf16 conversions --------------
// Edges are packed src|dst<<16 (n<=65536), bucket = dst>>8. Each 4096-edge
// block sorts its edges by bucket in LDS, reserves contiguous per-bucket
// global ranges, then streams the staged list out in order -> stores land in
// ~21-entry contiguous runs (r6 measured: naive 4-B scatter amplifies 3.2 MB
// of payload into 53 MB of HBM writes; this kills that).

__global__ __launch_bounds__(512) void prep_kernel(
    const int* __restrict__ ei, int E, int NB, int CAP, int p1blk,
    int* __restrict__ fill, uint32_t* __restrict__ bins,
    const float* __restrict__ x,
    const float* __restrict__ w0, const float* __restrict__ w1,
    const float* __restrict__ w2, const float* __restrict__ w3,
    const float* __restrict__ w4, const float* __restrict__ w5,
    uint16_t* __restrict__ xb, uint16_t* __restrict__ wb, int nx){
  if ((int)blockIdx.x < p1blk){
    __shared__ int hist[256], scn[256], cursor[256], gbase[256], excl[256];
    __shared__ uint32_t stage[4096];
    int tid = threadIdx.x;
    if (tid < 256) hist[tid] = 0;
    __syncthreads();
    int e0 = blockIdx.x * 4096;
    int nval = E - e0; if (nval > 4096) nval = 4096;
    uint32_t w[8]; int bk[8];
    #pragma unroll
    for (int k = 0; k < 8; ++k){
      int e = e0 + k * 512 + tid;
      bool ok = e < E;
      int s = ok ? __builtin_nontemporal_load(ei + e) : 0;
      int d = ok ? __builtin_nontemporal_load(ei + E + e) : 0;
      w[k] = (uint32_t)s | ((uint32_t)d << 16);
      bk[k] = ok ? (d >> 8) : -1;
      if (ok) atomicAdd(&hist[bk[k]], 1);
    }
    __syncthreads();
    if (tid < 256) scn[tid] = hist[tid];
    __syncthreads();
    #pragma unroll
    for (int off = 1; off < 256; off <<= 1){
      int v = 0;
      if (tid < 256 && tid >= off) v = scn[tid - off];
      __syncthreads();
      if (tid < 256) scn[tid] += v;
      __syncthreads();
    }
    if (tid < 256){
      int ex = scn[tid] - hist[tid];
      excl[tid] = ex; cursor[tid] = ex;
      gbase[tid] = (tid < NB && hist[tid] > 0)
                   ? atomicAdd(&fill[tid], hist[tid]) : 0;
    }
    __syncthreads();
    #pragma unroll
    for (int k = 0; k < 8; ++k){
      if (bk[k] >= 0){
        int p = atomicAdd(&cursor[bk[k]], 1);
        stage[p] = w[k];
      }
    }
    __syncthreads();
    for (int i = tid; i < nval; i += 512){
      uint32_t v = stage[i];
      int b = v >> 24;                    // dst>>8 (dst<65536)
      int loc = gbase[b] + (i - excl[b]);
      if (loc < CAP)
        __builtin_nontemporal_store(v, bins + (size_t)b * CAP + loc);
    }
  } else {
    int i = (blockIdx.x - p1blk) * 512 + threadIdx.x;
    int stride = (gridDim.x - p1blk) * 512;
    // x fp32 -> bf16 row-major; NT f32x4 reads (one-shot stream), uint2 out
    const f32x4* xv4 = (const f32x4*)x;
    for (int j = i; j < (nx >> 2); j += stride){
      f32x4 v = __builtin_nontemporal_load(xv4 + j);
      uint2 o;
      o.x = pack2(v.x, v.y); o.y = pack2(v.z, v.w);
      ((uint2*)xb)[j] = o;
    }
    const int WSZ = 128 * 128;
    for (int j = i; j < 6 * WSZ; j += stride){
      int t = j >> 14, o = j & (WSZ - 1);
      const float* w = t == 0 ? w0 : t == 1 ? w1 : t == 2 ? w2 : t == 3 ? w3 : t == 4 ? w4 : w5;
      wb[j] = f2bf(w[o]);
    }
  }
}

// ---- build: per-bucket CSR via LDS reorder + dense coalesced dump ----------
// One WG per 256-node bucket: hist by node, scan, place src into node-sorted
// LDS stage, then esrc[gb+i] = stage[i] fully coalesced (no 4-B scatter).
// esrc is uint16 (src < 65536): halves the dump write + both agg re-reads.

__global__ __launch_bounds__(512) void build_kernel(const uint32_t* __restrict__ bins,
                                                    const int* __restrict__ fill,
                                                    int CAP, int n,
                                                    int2* __restrict__ rowptr2,
                                                    uint16_t* __restrict__ esrc){
  __shared__ int hist[256], scn[256], cursor[256];
  __shared__ uint32_t stage[5120];
  int b = blockIdx.x, tid = threadIdx.x;
  int cnt = fill[b]; if (cnt > CAP) cnt = CAP;
  size_t gb = (size_t)b * CAP;
  if (tid < 256) hist[tid] = 0;
  __syncthreads();
  for (int i = tid; i < cnt; i += 512)
    atomicAdd(&hist[(__builtin_nontemporal_load(bins + gb + i) >> 16) & 255], 1);
  __syncthreads();
  if (tid < 256) scn[tid] = hist[tid];
  __syncthreads();
  #pragma unroll
  for (int off = 1; off < 256; off <<= 1){
    int v = 0;
    if (tid < 256 && tid >= off) v = scn[tid - off];
    __syncthreads();
    if (tid < 256) scn[tid] += v;
    __syncthreads();
  }
  if (tid < 256){
    int ex = scn[tid] - hist[tid];
    cursor[tid] = ex;
    int node = (b << 8) + tid;
    if (node < n) rowptr2[node] = make_int2((int)gb + ex, (int)gb + scn[tid]);
  }
  __syncthreads();
  for (int i = tid; i < cnt; i += 512){
    uint32_t v = __builtin_nontemporal_load(bins + gb + i);
    int p = atomicAdd(&cursor[(v >> 16) & 255], 1);
    stage[p] = v & 0xffffu;
  }
  __syncthreads();
  for (int i = tid; i < cnt; i += 512)
    esrc[gb + i] = (uint16_t)stage[i];     // consecutive i -> coalesced u16
}

// ---- mean aggregation: one wave per NODE, 16 row-gathers in flight ---------
// r0-proven shape: bf16 rows (256B), 16B/lane, 16 lanes/row, 4 edge slots x
// 4-deep unroll. Massive TLP (12.5k blocks, 0 LDS) keeps the random row-
// gather at its ~4.9 TB/s effective fabric ceiling — do not fuse this
// (r4/r10), do not re-layout it (r1/r2/r3), do not grid-sync it (r9).

__global__ __launch_bounds__(256) void agg_kernel(const uint16_t* __restrict__ xin,
                                                  const int2* __restrict__ rowptr2,
                                                  const uint16_t* __restrict__ esrc,
                                                  uint16_t* __restrict__ aggw, int n){
  int node = blockIdx.x * 4 + (threadIdx.x >> 6);
  if (node >= n) return;
  int lane = threadIdx.x & 63;
  int sub = lane >> 4, fq = lane & 15;
  const uint4* xv = (const uint4*)xin;              // row = 16 x uint4
  int2 be = rowptr2[node];
  int beg = be.x, end = be.y;
  float inv = 1.f / fmaxf((float)(end - beg), 1.f);
  float a[8] = {0.f,0.f,0.f,0.f,0.f,0.f,0.f,0.f};
  int e = beg + sub;
  for (; e + 12 < end; e += 16){
    int s0 = esrc[e], s1 = esrc[e + 4], s2 = esrc[e + 8], s3 = esrc[e + 12];
    uint4 v0 = xv[(size_t)s0 * 16 + fq];
    uint4 v1 = xv[(size_t)s1 * 16 + fq];
    uint4 v2 = xv[(size_t)s2 * 16 + fq];
    uint4 v3 = xv[(size_t)s3 * 16 + fq];
    accum8(v0, a); accum8(v1, a); accum8(v2, a); accum8(v3, a);
  }
  for (; e < end; e += 4){
    uint4 v = xv[(size_t)esrc[e] * 16 + fq];
    accum8(v, a);
  }
  #pragma unroll
  for (int i = 0; i < 8; ++i){
    a[i] += __shfl_xor(a[i], 16);
    a[i] += __shfl_xor(a[i], 32);
    a[i] *= inv;
  }
  if (sub == 0){
    uint4 o;
    o.x = pack2(a[0], a[1]); o.y = pack2(a[2], a[3]);
    o.z = pack2(a[4], a[5]); o.w = pack2(a[6], a[7]);
    ((uint4*)aggw)[(size_t)node * 16 + fq] = o;
  }
}

// ---- weight-staged GEMM tiles (verbatim r7) --------------------------------
// Block = 256 thr (4 waves) owns 64 rows and loops over ALL weight phases
// in-kernel: A-fragments loaded ONCE into registers; each 64-col weight slice
// staged into re-used LDS (34.8 KB -> 4 blocks/CU).
// MFMA 16x16x32 bf16, HW-verified layouts: A[m=lane&15][k=quad*8+j];
// B[k][n=lane&15] from W[col][k]; C/D col=lane&15, row=quad*4+reg.

#define WT_STRIDE 136   // shorts per staged weight row (128 + 8 pad)

__device__ __forceinline__ void stage_weights(const uint16_t* __restrict__ Wl,
                                              const uint16_t* __restrict__ Wr,
                                              int ch, uint16_t* lds_l,
                                              uint16_t* lds_r, int tid){
  const uint4* srcL = (const uint4*)(Wl + (size_t)(ch * 64) * 128);
  const uint4* srcR = (const uint4*)(Wr + (size_t)(ch * 64) * 128);
  #pragma unroll
  for (int i = 0; i < 4; ++i){          // 1024 uint4 per matrix / 256 thr
    int j = tid + i * 256;
    int row = j >> 4, c8 = j & 15;      // 16 uint4 per 128-col row
    uint4 vl = srcL[j], vr = srcR[j];
    *(uint4*)(lds_l + row * WT_STRIDE + c8 * 8) = vl;
    *(uint4*)(lds_r + row * WT_STRIDE + c8 * 8) = vr;
  }
}

// layer 1: x1 = relu(agg@W1l^T + b1 + x@W1r^T), bf16 out. ch looped in-kernel.
__global__ __launch_bounds__(256) void gemm1_kernel(
    const uint16_t* __restrict__ Aagg, const uint16_t* __restrict__ Ax,
    const uint16_t* __restrict__ Wl, const uint16_t* __restrict__ Wr,
    const float* __restrict__ bias, uint16_t* __restrict__ x1b, int n){
  __shared__ uint16_t lds_l[64 * WT_STRIDE], lds_r[64 * WT_STRIDE];
  int tid = threadIdx.x, lane = tid & 63, wid = tid >> 6;
  int m = lane & 15, quad = lane >> 4;
  int r0 = blockIdx.x * 64 + wid * 16;
  int arow = r0 + m; if (arow > n - 1) arow = n - 1;   // clamp tail reads

  short8 a0f[4], a1f[4];
  #pragma unroll
  for (int ks = 0; ks < 4; ++ks){
    a0f[ks] = *(const short8*)(Aagg + (size_t)arow * 128 + ks * 32 + quad * 8);
    a1f[ks] = *(const short8*)(Ax   + (size_t)arow * 128 + ks * 32 + quad * 8);
  }

  for (int ch = 0; ch < 2; ++ch){
    if (ch) __syncthreads();              // prior phase's LDS reads done
    stage_weights(Wl, Wr, ch, lds_l, lds_r, tid);
    __syncthreads();
    float4v acc[4];
    #pragma unroll
    for (int ct = 0; ct < 4; ++ct) acc[ct] = (float4v){0.f, 0.f, 0.f, 0.f};
    #pragma unroll
    for (int ks = 0; ks < 4; ++ks){
      #pragma unroll
      for (int ct = 0; ct < 4; ++ct){
        short8 b0 = *(const short8*)(lds_l + (ct * 16 + m) * WT_STRIDE + ks * 32 + quad * 8);
        acc[ct] = __builtin_amdgcn_mfma_f32_16x16x32_bf16(a0f[ks], b0, acc[ct], 0, 0, 0);
        short8 b1 = *(const short8*)(lds_r + (ct * 16 + m) * WT_STRIDE + ks * 32 + quad * 8);
        acc[ct] = __builtin_amdgcn_mfma_f32_16x16x32_bf16(a1f[ks], b1, acc[ct], 0, 0, 0);
      }
    }
    #pragma unroll
    for (int ct = 0; ct < 4; ++ct){
      int col = ch * 64 + ct * 16 + m;
      float bv = bias[col];
      #pragma unroll
      for (int i = 0; i < 4; ++i){
        int grow = r0 + quad * 4 + i;
        if (grow < n)
          x1b[(size_t)grow * 128 + col] = f2bf(fmaxf(acc[ct][i] + bv, 0.f));
      }
    }
  }
}

// layers 2+3: all 4 (pass, ch) phases looped in-kernel; A read once. fp32 out.
__global__ __launch_bounds__(256) void gemm23_kernel(
    const uint16_t* __restrict__ Aagg, const uint16_t* __restrict__ Ax,
    const uint16_t* __restrict__ W2l, const uint16_t* __restrict__ W2r,
    const float* __restrict__ b2,
    const uint16_t* __restrict__ W3l, const uint16_t* __restrict__ W3r,
    const float* __restrict__ b3,
    float* __restrict__ out, size_t half, int n){
  __shared__ uint16_t lds_l[64 * WT_STRIDE], lds_r[64 * WT_STRIDE];
  int tid = threadIdx.x, lane = tid & 63, wid = tid >> 6;
  int m = lane & 15, quad = lane >> 4;
  int r0 = blockIdx.x * 64 + wid * 16;
  int arow = r0 + m; if (arow > n - 1) arow = n - 1;

  short8 a0f[4], a1f[4];
  #pragma unroll
  for (int ks = 0; ks < 4; ++ks){
    a0f[ks] = *(const short8*)(Aagg + (size_t)arow * 128 + ks * 32 + quad * 8);
    a1f[ks] = *(const short8*)(Ax   + (size_t)arow * 128 + ks * 32 + quad * 8);
  }

  for (int idx = 0; idx < 4; ++idx){
    int pass = idx >> 1, ch = idx & 1;
    if (idx) __syncthreads();
    stage_weights(pass ? W3l : W2l, pass ? W3r : W2r, ch, lds_l, lds_r, tid);
    __syncthreads();
    float4v acc[4];
    #pragma unroll
    for (int ct = 0; ct < 4; ++ct) acc[ct] = (float4v){0.f, 0.f, 0.f, 0.f};
    #pragma unroll
    for (int ks = 0; ks < 4; ++ks){
      #pragma unroll
      for (int ct = 0; ct < 4; ++ct){
        short8 b0 = *(const short8*)(lds_l + (ct * 16 + m) * WT_STRIDE + ks * 32 + quad * 8);
        acc[ct] = __builtin_amdgcn_mfma_f32_16x16x32_bf16(a0f[ks], b0, acc[ct], 0, 0, 0);
        short8 b1 = *(const short8*)(lds_r + (ct * 16 + m) * WT_STRIDE + ks * 32 + quad * 8);
        acc[ct] = __builtin_amdgcn_mfma_f32_16x16x32_bf16(a1f[ks], b1, acc[ct], 0, 0, 0);
      }
    }
    const float* bb = pass ? b3 : b2;
    float* op = out + (pass ? half : 0);
    #pragma unroll
    for (int ct = 0; ct < 4; ++ct){
      int col = ch * 64 + ct * 16 + m;
      float bv = bb[col];
      #pragma unroll
      for (int i = 0; i < 4; ++i){
        int grow = r0 + quad * 4 + i;
        if (grow < n)
          __builtin_nontemporal_store(acc[ct][i] + bv,
                                      op + (size_t)grow * 128 + col);
      }
    }
  }
}

// ---- launcher --------------------------------------------------------------

extern "C" void kernel_launch(void* const* d_in, const int* in_sizes, int n_in,
                              void* d_out, int out_size, void* d_ws, size_t ws_size,
                              hipStream_t stream) {
  const float* x   = (const float*)d_in[0];   // fp32 [N,128]
  const int*   ei  = (const int*)d_in[1];     // int32 [2,E]
  const float* W1l = (const float*)d_in[2];
  const float* b1l = (const float*)d_in[3];
  const float* W1r = (const float*)d_in[4];
  const float* W2l = (const float*)d_in[5];
  const float* b2l = (const float*)d_in[6];
  const float* W2r = (const float*)d_in[7];
  const float* W3l = (const float*)d_in[8];
  const float* b3l = (const float*)d_in[9];
  const float* W3r = (const float*)d_in[10];
  float* out = (float*)d_out;

  const int n = in_sizes[0] / 128;
  const int E = in_sizes[1] / 2;
  const size_t half = (size_t)n * 128;        // elements per output half
  const int WSZ = 128 * 128;

  const int NB = (n + 255) >> 8;              // 256-node buckets (n <= 65536)
  int mean = (E + NB - 1) / NB;
  int CAP = mean + 8 * (int)sqrt((double)mean) + 64;
  CAP = (CAP + 63) & ~63;                     // per-bucket capacity, 8-sigma slack
  if (CAP > 5120) CAP = 5120;                 // build LDS stage bound

  size_t off = 0;
  auto carve = [&](size_t bytes) -> void* {
    void* p = (char*)d_ws + off;
    off += (bytes + 255) & ~(size_t)255;
    return p;
  };
  int2*     rowptr2 = (int2*)carve((size_t)n * 8);
  int*      fill    = (int*)carve((size_t)NB * 4);
  uint16_t* esrc    = (uint16_t*)carve((size_t)NB * CAP * 2);
  uint16_t* xb      = (uint16_t*)carve(half * 2);            // bf16 x
  uint16_t* wb      = (uint16_t*)carve((size_t)6 * WSZ * 2); // bf16 weights
  uint16_t* x1b     = (uint16_t*)carve(half * 2);            // bf16 x1
  uint16_t* agg     = (uint16_t*)carve(half * 2);            // bf16 agg
  uint32_t* bins    = (uint32_t*)carve((size_t)NB * CAP * 4);// packed staging
  (void)ws_size;  // measured ws_size = 256 MiB >> ~35 MB used

  (void)hipMemsetAsync(fill, 0, (size_t)NB * 4, stream);

  int p1blk = (E + 4095) / 4096;              // 4096 edges per binning block
  int cblk  = 512;                            // conversion blocks (grid-stride)
  prep_kernel<<<p1blk + cblk, 512, 0, stream>>>(ei, E, NB, CAP, p1blk, fill, bins,
                                                x, W1l, W1r, W2l, W2r, W3l, W3r,
                                                xb, wb, (int)half);
  build_kernel<<<NB, 512, 0, stream>>>(bins, fill, CAP, n, rowptr2, esrc);

  int ablk = (n + 3) / 4;
  int gblk = (n + 63) / 64;
  const uint16_t *Wb1l = wb, *Wb1r = wb + WSZ, *Wb2l = wb + 2 * WSZ,
                 *Wb2r = wb + 3 * WSZ, *Wb3l = wb + 4 * WSZ, *Wb3r = wb + 5 * WSZ;

  // layer 1
  agg_kernel<<<ablk, 256, 0, stream>>>(xb, rowptr2, esrc, agg, n);
  gemm1_kernel<<<gblk, 256, 0, stream>>>(agg, xb, Wb1l, Wb1r, b1l, x1b, n);

  // shared aggregation of x1, then layers 2+3 in one launch
  agg_kernel<<<ablk, 256, 0, stream>>>(x1b, rowptr2, esrc, agg, n);
  gemm23_kernel<<<gblk, 256, 0, stream>>>(agg, x1b, Wb2l, Wb2r, b2l,
                                          Wb3l, Wb3r, b3l, out, half, n);
}